// Round 1
// baseline (19269.931 us; speedup 1.0000x reference)
//
#include <hip/hip_runtime.h>
#include <hip/hip_bf16.h>
#include <hip/hip_cooperative_groups.h>

namespace cg = cooperative_groups;

#define EMBED 128
#define HID   256
#define BB    256   // batch
#define TT    512   // time
#define G4    1024  // 4*HID

typedef __attribute__((ext_vector_type(8))) short short8;
typedef __attribute__((ext_vector_type(4))) float f32x4;

// ---- workspace layout (bytes) ----
// WUp   : [dir][jg][c:128][k:384] bf16, c = gate*32 + jc; k<128 -> W[k][J], k>=128 -> U[k-128][J]
//         J = gate*256 + jg*32 + jc
// bp    : [dir][jg][c:128] f32
// xhat  : [B][T][128] bf16   (embedded inputs)
// hbuf  : [dir][parity][B][HID] bf16
// hfinal: [dir][B][HID] f32
#define OFF_WUP   0
#define SZ_WUP    (2*8*128*384*2)            // 1,572,864
#define OFF_BP    (OFF_WUP + SZ_WUP)
#define SZ_BP     (2*8*128*4)                // 8,192
#define OFF_XHAT  (OFF_BP + SZ_BP)
#define SZ_XHAT   ((size_t)BB*TT*EMBED*2)    // 33,554,432
#define OFF_HBUF  (OFF_XHAT + SZ_XHAT)
#define SZ_HBUF   (2*2*BB*HID*2)             // 524,288
#define OFF_HFIN  (OFF_HBUF + SZ_HBUF)
#define SZ_HFIN   (2*BB*HID*4)               // 524,288

__global__ void pack_kernel(const float* __restrict__ Wf, const float* __restrict__ Uf,
                            const float* __restrict__ bf,
                            const float* __restrict__ Wb, const float* __restrict__ Ub,
                            const float* __restrict__ bb,
                            __hip_bfloat16* __restrict__ WUp, float* __restrict__ bp) {
    int flat = blockIdx.x * 256 + threadIdx.x;          // [0, 2*8*128*384)
    int k = flat % 384;
    int rest = flat / 384;                              // (dir*8+jg)*128 + c
    int c = rest % 128;
    int jgd = rest / 128;                               // dir*8 + jg
    int jg = jgd & 7, dir = jgd >> 3;
    int J = (c >> 5) * 256 + jg * 32 + (c & 31);
    const float* W = dir ? Wb : Wf;
    const float* U = dir ? Ub : Uf;
    float v = (k < 128) ? W[(size_t)k * G4 + J] : U[(size_t)(k - 128) * G4 + J];
    WUp[flat] = __float2bfloat16(v);
    if (k == 0) {
        const float* bias = dir ? bb : bf;
        bp[rest] = bias[J];
    }
}

__global__ void gather_kernel(const int* __restrict__ inputs, const float* __restrict__ embed,
                              __hip_bfloat16* __restrict__ xhat) {
    int row = blockIdx.x * 2 + (threadIdx.x >> 7);      // [0, B*T)
    int col = threadIdx.x & 127;
    int tok = inputs[row];
    xhat[(size_t)row * EMBED + col] = __float2bfloat16(embed[(size_t)tok * EMBED + col]);
}

__launch_bounds__(256, 1)
__global__ void lstm_kernel(const int* __restrict__ inputs,
                            const __hip_bfloat16* __restrict__ xhat,
                            const __hip_bfloat16* __restrict__ WUp,
                            const float* __restrict__ bp,
                            __hip_bfloat16* __restrict__ hbuf,
                            float* __restrict__ hfinal) {
    cg::grid_group grid = cg::this_grid();
    extern __shared__ char smem[];
    __hip_bfloat16* a_tile = (__hip_bfloat16*)smem;              // [16][392] bf16 = 12544 B
    float* ig_tile = (float*)(smem + 12544);                     // [16][33] f32 = 2112 B
    int* mask_s = (int*)(smem + 12544 + 2112);                   // [16] int

    const int bid = blockIdx.x;
    const int dir = bid >> 7;            // 0 fwd, 1 bwd
    const int jg  = (bid >> 4) & 7;      // gate-column group (32 h-cols)
    const int bg  = bid & 15;            // batch group (16 rows)
    const int tid = threadIdx.x;
    const int wid = tid >> 6;            // wave 0..3
    const int lane = tid & 63;
    const int l15 = lane & 15, lhi = lane >> 4;

    // Preload this wave's weight (B) fragments into registers; n-tiles {wid, wid+4}.
    // n-tile n covers local cols [16n,16n+16): n<2 -> i, n in {2,3} -> f, {4,5} -> g, {6,7} -> o
    short8 bfrag0[12], bfrag1[12];
    const short* wu = (const short*)WUp + (size_t)(dir * 8 + jg) * 128 * 384;
#pragma unroll
    for (int kt = 0; kt < 12; ++kt) {
        bfrag0[kt] = *(const short8*)(wu + (size_t)(16 * wid + l15) * 384 + kt * 32 + 8 * lhi);
        bfrag1[kt] = *(const short8*)(wu + (size_t)(16 * (wid + 4) + l15) * 384 + kt * 32 + 8 * lhi);
    }
    const float bias0 = bp[(dir * 8 + jg) * 128 + 16 * wid + l15];
    const float bias1 = bp[(dir * 8 + jg) * 128 + 16 * (wid + 4) + l15];

    float c_st[4] = {0, 0, 0, 0};   // waves 2,3: cell state for (b = 4*lhi+r, jc)
    float h_st[4] = {0, 0, 0, 0};   // carried hidden state (fp32)
    const int jc = (wid & 1) * 16 + l15;

    const __hip_bfloat16* hb_base = hbuf + (size_t)dir * 2 * BB * HID;

    for (int s = 0; s < TT; ++s) {
        const int t = dir ? (TT - 1 - s) : s;
        grid.sync();
        // ---- load A tile: x_t -> cols [0,128), h(s) -> cols [128,384) ----
        {
            int r = tid >> 4, seg = tid & 15;
            int b = bg * 16 + r;
            *(short8*)((short*)a_tile + r * 392 + seg * 8) =
                *(const short8*)((const short*)xhat + ((size_t)b * TT + t) * EMBED + seg * 8);
            const short* hrow = (const short*)hb_base + (size_t)(s & 1) * BB * HID + (size_t)b * HID;
            *(short8*)((short*)a_tile + r * 392 + 128 + seg * 16)     = *(const short8*)(hrow + seg * 16);
            *(short8*)((short*)a_tile + r * 392 + 128 + seg * 16 + 8) = *(const short8*)(hrow + seg * 16 + 8);
            if (tid < 16) mask_s[tid] = (inputs[(size_t)(bg * 16 + tid) * TT + t] > 0) ? 1 : 0;
        }
        __syncthreads();
        // ---- MFMA: D[16 batch][16 j] over K=384 ----
        f32x4 acc0 = {0, 0, 0, 0}, acc1 = {0, 0, 0, 0};
#pragma unroll
        for (int kt = 0; kt < 12; ++kt) {
            short8 a = *(const short8*)((const short*)a_tile + l15 * 392 + kt * 32 + 8 * lhi);
            acc0 = __builtin_amdgcn_mfma_f32_16x16x32_bf16(a, bfrag0[kt], acc0, 0, 0, 0);
            acc1 = __builtin_amdgcn_mfma_f32_16x16x32_bf16(a, bfrag1[kt], acc1, 0, 0, 0);
        }
        // ---- gates ----
        if (wid < 2) {          // waves 0,1: acc0 = i-gate, acc1 = g-gate  -> ig = sig(i)*tanh(g)
#pragma unroll
            for (int r = 0; r < 4; ++r) {
                int b = 4 * lhi + r;
                float zi = acc0[r] + bias0;
                float zg = acc1[r] + bias1;
                float ig = (1.f / (1.f + __expf(-zi))) * tanhf(zg);
                ig_tile[b * 33 + jc] = ig;
            }
        }
        __syncthreads();
        if (wid >= 2) {         // waves 2,3: acc0 = f-gate, acc1 = o-gate; own (c,h)
            __hip_bfloat16* hw = hbuf + (size_t)dir * 2 * BB * HID + (size_t)((s + 1) & 1) * BB * HID;
#pragma unroll
            for (int r = 0; r < 4; ++r) {
                int b = 4 * lhi + r;
                float zf = acc0[r] + bias0;
                float zo = acc1[r] + bias1;
                float ig = ig_tile[b * 33 + jc];
                float cn = (1.f / (1.f + __expf(-zf))) * c_st[r] + ig;
                float hn = (1.f / (1.f + __expf(-zo))) * tanhf(cn);
                if (mask_s[b]) { c_st[r] = cn; h_st[r] = hn; }
                hw[(size_t)(bg * 16 + b) * HID + jg * 32 + jc] = __float2bfloat16(h_st[r]);
            }
            __threadfence();   // release h(s+1) before the next grid.sync
        }
    }
    if (wid >= 2) {
#pragma unroll
        for (int r = 0; r < 4; ++r) {
            int b = 4 * lhi + r;
            hfinal[((size_t)dir * BB + bg * 16 + b) * HID + jg * 32 + jc] = h_st[r];
        }
    }
}

__global__ void epilogue_kernel(const int* __restrict__ input_end,
                                const float* __restrict__ hfinal,
                                const float* __restrict__ cls_W, const float* __restrict__ cls_b,
                                const float* __restrict__ ent_W, const float* __restrict__ ent_b,
                                float* __restrict__ out) {
    int b = blockIdx.x;
    int lane = threadIdx.x;   // 64 threads
    int ie = input_end[b];
    float pe0 = 0, pe1 = 0, pe2 = 0, pc = 0;
    for (int k = lane; k < 2 * HID; k += 64) {
        float bv, se;
        if (k < HID) {
            bv = hfinal[(size_t)b * HID + k];
            se = hfinal[(size_t)ie * HID + k];
        } else {
            bv = hfinal[(size_t)(BB + b) * HID + (k - HID)];
            se = hfinal[(size_t)(BB + ie) * HID + (k - HID)];
        }
        pe0 += bv * ent_W[k * 3 + 0];
        pe1 += bv * ent_W[k * 3 + 1];
        pe2 += bv * ent_W[k * 3 + 2];
        pc  += se * cls_W[k];
    }
    for (int off = 32; off; off >>= 1) {
        pe0 += __shfl_down(pe0, off);
        pe1 += __shfl_down(pe1, off);
        pe2 += __shfl_down(pe2, off);
        pc  += __shfl_down(pc, off);
    }
    if (lane == 0) {
        float l0 = pe0 + ent_b[0], l1 = pe1 + ent_b[1], l2 = pe2 + ent_b[2];
        float m = fmaxf(l0, fmaxf(l1, l2));
        float e0 = __expf(l0 - m), e1 = __expf(l1 - m), e2 = __expf(l2 - m);
        float ssum = e0 + e1 + e2;
        out[256 + b * 3 + 0] = e0 / ssum;
        out[256 + b * 3 + 1] = e1 / ssum;
        out[256 + b * 3 + 2] = e2 / ssum;
        float cl = pc + cls_b[0];
        out[b] = 1.f / (1.f + __expf(-cl));
    }
}

extern "C" void kernel_launch(void* const* d_in, const int* in_sizes, int n_in,
                              void* d_out, int out_size, void* d_ws, size_t ws_size,
                              hipStream_t stream) {
    const int*   inputs    = (const int*)d_in[0];
    const int*   input_end = (const int*)d_in[1];
    const float* embed     = (const float*)d_in[2];
    const float* Wf        = (const float*)d_in[3];
    const float* Uf        = (const float*)d_in[4];
    const float* bf        = (const float*)d_in[5];
    const float* Wb        = (const float*)d_in[6];
    const float* Ub        = (const float*)d_in[7];
    const float* bb        = (const float*)d_in[8];
    const float* cls_W     = (const float*)d_in[9];
    const float* cls_b     = (const float*)d_in[10];
    const float* ent_W     = (const float*)d_in[11];
    const float* ent_b     = (const float*)d_in[12];
    float* out = (float*)d_out;

    char* ws = (char*)d_ws;
    __hip_bfloat16* WUp    = (__hip_bfloat16*)(ws + OFF_WUP);
    float*          bp     = (float*)(ws + OFF_BP);
    __hip_bfloat16* xhat   = (__hip_bfloat16*)(ws + OFF_XHAT);
    __hip_bfloat16* hbuf   = (__hip_bfloat16*)(ws + OFF_HBUF);
    float*          hfinal = (float*)(ws + OFF_HFIN);

    hipMemsetAsync(hbuf, 0, SZ_HBUF, stream);
    pack_kernel<<<3072, 256, 0, stream>>>(Wf, Uf, bf, Wb, Ub, bb, WUp, bp);
    gather_kernel<<<BB * TT / 2, 256, 0, stream>>>(inputs, embed, xhat);

    void* args[] = {(void*)&inputs, (void*)&xhat, (void*)&WUp, (void*)&bp,
                    (void*)&hbuf, (void*)&hfinal};
    hipLaunchCooperativeKernel((void*)lstm_kernel, dim3(256), dim3(256), args,
                               12544 + 2112 + 64, stream);

    epilogue_kernel<<<BB, 64, 0, stream>>>(input_end, hfinal, cls_W, cls_b, ent_W, ent_b, out);
}

// Round 2
// 8672.422 us; speedup vs baseline: 2.2220x; 2.2220x over previous
//
#include <hip/hip_runtime.h>
#include <hip/hip_bf16.h>
#include <hip/hip_cooperative_groups.h>

#define EMBED 128
#define HID   256
#define BB    256   // batch
#define TT    512   // time
#define G4    1024  // 4*HID

typedef __attribute__((ext_vector_type(8))) short short8;
typedef __attribute__((ext_vector_type(4))) float f32x4;

// ---- workspace layout (bytes) ----
// WUp   : [dir][jg][gate][jc:32][k:384] bf16 ; J = gate*256 + jg*32 + jc
//         k<128 -> W[k][J], k>=128 -> U[k-128][J]
// bp    : [dir][jg][gate][jc:32] f32
// xhat  : [B][T][128] bf16   (embedded inputs)
// hbuf  : [dir][parity][B][HID] bf16
// hfinal: [dir][B][HID] f32
// flags : [dir][jg][bg] int, padded to 32 ints (128B) each
#define OFF_WUP   0
#define SZ_WUP    (2*8*4*32*384*2)           // 1,572,864
#define OFF_BP    (OFF_WUP + SZ_WUP)
#define SZ_BP     (2*8*4*32*4)               // 4,096
#define OFF_XHAT  (OFF_BP + SZ_BP)
#define SZ_XHAT   ((size_t)BB*TT*EMBED*2)    // 33,554,432
#define OFF_HBUF  (OFF_XHAT + SZ_XHAT)
#define SZ_HBUF   (2*2*BB*HID*2)             // 524,288
#define OFF_HFIN  (OFF_HBUF + SZ_HBUF)
#define SZ_HFIN   (2*BB*HID*4)               // 524,288
#define OFF_FLAGS (OFF_HFIN + SZ_HFIN)
#define SZ_FLAGS  (2*8*8*32*4)               // 16,384

__global__ void pack_kernel(const float* __restrict__ Wf, const float* __restrict__ Uf,
                            const float* __restrict__ bf,
                            const float* __restrict__ Wb, const float* __restrict__ Ub,
                            const float* __restrict__ bb,
                            __hip_bfloat16* __restrict__ WUp, float* __restrict__ bp) {
    int flat = blockIdx.x * 256 + threadIdx.x;          // [0, 2*8*4*32*384)
    int k = flat % 384;
    int rest = flat / 384;                              // [dir][jg][gate][jc]
    int jc   = rest & 31;
    int gate = (rest >> 5) & 3;
    int jg   = (rest >> 7) & 7;
    int dir  = rest >> 10;
    int J = gate * 256 + jg * 32 + jc;
    const float* W = dir ? Wb : Wf;
    const float* U = dir ? Ub : Uf;
    float v = (k < 128) ? W[(size_t)k * G4 + J] : U[(size_t)(k - 128) * G4 + J];
    WUp[flat] = __float2bfloat16(v);
    if (k == 0) {
        const float* bias = dir ? bb : bf;
        bp[rest] = bias[J];
    }
}

__global__ void gather_kernel(const int* __restrict__ inputs, const float* __restrict__ embed,
                              __hip_bfloat16* __restrict__ xhat) {
    int row = blockIdx.x * 2 + (threadIdx.x >> 7);      // [0, B*T)
    int col = threadIdx.x & 127;
    int tok = inputs[row];
    xhat[(size_t)row * EMBED + col] = __float2bfloat16(embed[(size_t)tok * EMBED + col]);
}

__device__ __forceinline__ float sigf(float x) { return 1.f / (1.f + __expf(-x)); }

__launch_bounds__(256, 1)
__global__ void lstm_kernel(const int* __restrict__ inputs,
                            const __hip_bfloat16* __restrict__ xhat,
                            const __hip_bfloat16* __restrict__ WUp,
                            const float* __restrict__ bp,
                            __hip_bfloat16* __restrict__ hbuf,
                            float* __restrict__ hfinal,
                            int* __restrict__ flags) {
    const int bid = blockIdx.x;          // 128 blocks = 2 dir x 8 jg x 8 bg
    const int dir = bid >> 6;
    const int jg  = (bid >> 3) & 7;
    const int bg  = bid & 7;
    const int tid = threadIdx.x;
    const int wid = tid >> 6;            // wave 0..3
    const int lane = tid & 63;
    const int l15 = lane & 15, lhi = lane >> 4;
    const int jch = wid & 1;             // jc half: cols jch*16 + l15
    const int mrow0 = bg * 32 + (wid >> 1) * 16;   // m-tile base (batch)

    // ---- preload weights: 4 gates x 12 k-tiles, stationary in VGPRs ----
    short8 wfrag[4][12];
    const short* wu = (const short*)WUp + (size_t)(dir * 8 + jg) * 4 * 32 * 384;
#pragma unroll
    for (int g = 0; g < 4; ++g)
#pragma unroll
        for (int kt = 0; kt < 12; ++kt)
            wfrag[g][kt] = *(const short8*)(wu + (size_t)(g * 32 + jch * 16 + l15) * 384 + kt * 32 + 8 * lhi);

    float bias[4];
#pragma unroll
    for (int g = 0; g < 4; ++g)
        bias[g] = bp[((dir * 8 + jg) * 4 + g) * 32 + jch * 16 + l15];

    float c_st[4] = {0, 0, 0, 0};
    float h_st[4] = {0, 0, 0, 0};
    int brow[4];
#pragma unroll
    for (int r = 0; r < 4; ++r) brow[r] = bg * 32 + (wid >> 1) * 16 + 4 * lhi + r;

    int* myflag = flags + ((dir * 8 + jg) * 8 + bg) * 32;
    int* pollp  = flags + ((dir * 8 + (lane & 7)) * 8 + bg) * 32;  // 8 producers of this (dir,bg)

    const short* xrow = (const short*)xhat + (size_t)(mrow0 + l15) * TT * EMBED;
    const short* hb   = (const short*)hbuf + (size_t)dir * 2 * BB * HID;

    for (int s = 0; s < TT; ++s) {
        const int t = dir ? (TT - 1 - s) : s;

        // ---- issue x-fragment + mask loads before the flag wait ----
        short8 af[12];
#pragma unroll
        for (int kt = 0; kt < 4; ++kt)
            af[kt] = *(const short8*)(xrow + (size_t)t * EMBED + kt * 32 + 8 * lhi);
        int mk[4];
#pragma unroll
        for (int r = 0; r < 4; ++r) mk[r] = inputs[(size_t)brow[r] * TT + t];

        // ---- wait for h(s) from the 8 producers of this (dir,bg) group ----
        int v;
        do {
            v = __hip_atomic_load(pollp, __ATOMIC_ACQUIRE, __HIP_MEMORY_SCOPE_AGENT);
        } while (__any(v < s));

        // ---- h fragments straight from global (L2) ----
        const short* hrow = hb + (size_t)(s & 1) * BB * HID + (size_t)(mrow0 + l15) * HID;
#pragma unroll
        for (int kt = 0; kt < 8; ++kt)
            af[4 + kt] = *(const short8*)(hrow + kt * 32 + 8 * lhi);

        // ---- MFMA: 4 gates x 12 k-tiles ----
        f32x4 acc[4] = {{0,0,0,0},{0,0,0,0},{0,0,0,0},{0,0,0,0}};
#pragma unroll
        for (int kt = 0; kt < 12; ++kt)
#pragma unroll
            for (int g = 0; g < 4; ++g)
                acc[g] = __builtin_amdgcn_mfma_f32_16x16x32_bf16(af[kt], wfrag[g][kt], acc[g], 0, 0, 0);

        // ---- gates: all wave-local ----
        __hip_bfloat16* hw = hbuf + (size_t)dir * 2 * BB * HID + (size_t)((s + 1) & 1) * BB * HID;
#pragma unroll
        for (int r = 0; r < 4; ++r) {
            float zi = acc[0][r] + bias[0];
            float zf = acc[1][r] + bias[1];
            float zg = acc[2][r] + bias[2];
            float zo = acc[3][r] + bias[3];
            float cn = sigf(zf) * c_st[r] + sigf(zi) * tanhf(zg);
            float hn = sigf(zo) * tanhf(cn);
            if (mk[r] > 0) { c_st[r] = cn; h_st[r] = hn; }
            hw[(size_t)brow[r] * HID + jg * 32 + jch * 16 + l15] = __float2bfloat16(h_st[r]);
        }

        // ---- publish h(s+1) ----
        __builtin_amdgcn_fence(__ATOMIC_RELEASE, "agent");
        __syncthreads();
        if (tid == 0)
            __hip_atomic_store(myflag, s + 1, __ATOMIC_RELEASE, __HIP_MEMORY_SCOPE_AGENT);
    }

#pragma unroll
    for (int r = 0; r < 4; ++r)
        hfinal[((size_t)dir * BB + brow[r]) * HID + jg * 32 + jch * 16 + l15] = h_st[r];
}

__global__ void epilogue_kernel(const int* __restrict__ input_end,
                                const float* __restrict__ hfinal,
                                const float* __restrict__ cls_W, const float* __restrict__ cls_b,
                                const float* __restrict__ ent_W, const float* __restrict__ ent_b,
                                float* __restrict__ out) {
    int b = blockIdx.x;
    int lane = threadIdx.x;   // 64 threads
    int ie = input_end[b];
    float pe0 = 0, pe1 = 0, pe2 = 0, pc = 0;
    for (int k = lane; k < 2 * HID; k += 64) {
        float bv, se;
        if (k < HID) {
            bv = hfinal[(size_t)b * HID + k];
            se = hfinal[(size_t)ie * HID + k];
        } else {
            bv = hfinal[(size_t)(BB + b) * HID + (k - HID)];
            se = hfinal[(size_t)(BB + ie) * HID + (k - HID)];
        }
        pe0 += bv * ent_W[k * 3 + 0];
        pe1 += bv * ent_W[k * 3 + 1];
        pe2 += bv * ent_W[k * 3 + 2];
        pc  += se * cls_W[k];
    }
    for (int off = 32; off; off >>= 1) {
        pe0 += __shfl_down(pe0, off);
        pe1 += __shfl_down(pe1, off);
        pe2 += __shfl_down(pe2, off);
        pc  += __shfl_down(pc, off);
    }
    if (lane == 0) {
        float l0 = pe0 + ent_b[0], l1 = pe1 + ent_b[1], l2 = pe2 + ent_b[2];
        float m = fmaxf(l0, fmaxf(l1, l2));
        float e0 = __expf(l0 - m), e1 = __expf(l1 - m), e2 = __expf(l2 - m);
        float ssum = e0 + e1 + e2;
        out[256 + b * 3 + 0] = e0 / ssum;
        out[256 + b * 3 + 1] = e1 / ssum;
        out[256 + b * 3 + 2] = e2 / ssum;
        float cl = pc + cls_b[0];
        out[b] = 1.f / (1.f + __expf(-cl));
    }
}

extern "C" void kernel_launch(void* const* d_in, const int* in_sizes, int n_in,
                              void* d_out, int out_size, void* d_ws, size_t ws_size,
                              hipStream_t stream) {
    const int*   inputs    = (const int*)d_in[0];
    const int*   input_end = (const int*)d_in[1];
    const float* embed     = (const float*)d_in[2];
    const float* Wf        = (const float*)d_in[3];
    const float* Uf        = (const float*)d_in[4];
    const float* bf        = (const float*)d_in[5];
    const float* Wb        = (const float*)d_in[6];
    const float* Ub        = (const float*)d_in[7];
    const float* bb        = (const float*)d_in[8];
    const float* cls_W     = (const float*)d_in[9];
    const float* cls_b     = (const float*)d_in[10];
    const float* ent_W     = (const float*)d_in[11];
    const float* ent_b     = (const float*)d_in[12];
    float* out = (float*)d_out;

    char* ws = (char*)d_ws;
    __hip_bfloat16* WUp    = (__hip_bfloat16*)(ws + OFF_WUP);
    float*          bp     = (float*)(ws + OFF_BP);
    __hip_bfloat16* xhat   = (__hip_bfloat16*)(ws + OFF_XHAT);
    __hip_bfloat16* hbuf   = (__hip_bfloat16*)(ws + OFF_HBUF);
    float*          hfinal = (float*)(ws + OFF_HFIN);
    int*            flags  = (int*)(ws + OFF_FLAGS);

    hipMemsetAsync(hbuf, 0, SZ_HBUF, stream);
    hipMemsetAsync(flags, 0, SZ_FLAGS, stream);
    pack_kernel<<<3072, 256, 0, stream>>>(Wf, Uf, bf, Wb, Ub, bb, WUp, bp);
    gather_kernel<<<BB * TT / 2, 256, 0, stream>>>(inputs, embed, xhat);

    void* args[] = {(void*)&inputs, (void*)&xhat, (void*)&WUp, (void*)&bp,
                    (void*)&hbuf, (void*)&hfinal, (void*)&flags};
    hipLaunchCooperativeKernel((void*)lstm_kernel, dim3(128), dim3(256), args, 0, stream);

    epilogue_kernel<<<BB, 64, 0, stream>>>(input_end, hfinal, cls_W, cls_b, ent_W, ent_b, out);
}

// Round 3
// 1667.929 us; speedup vs baseline: 11.5532x; 5.1995x over previous
//
#include <hip/hip_runtime.h>
#include <hip/hip_bf16.h>
#include <hip/hip_cooperative_groups.h>

#define EMBED 128
#define HID   256
#define BB    256   // batch
#define TT    512   // time
#define G4    1024  // 4*HID

typedef __attribute__((ext_vector_type(8))) short short8;
typedef __attribute__((ext_vector_type(4))) float f32x4;

// ---- workspace layout (bytes) ----
#define OFF_WUP   0
#define SZ_WUP    (2*8*4*32*384*2)           // 1,572,864
#define OFF_BP    (OFF_WUP + SZ_WUP)
#define SZ_BP     (2*8*4*32*4)               // 4,096
#define OFF_XHAT  (OFF_BP + SZ_BP)
#define SZ_XHAT   ((size_t)BB*TT*EMBED*2)    // 33,554,432
#define OFF_HBUF  (OFF_XHAT + SZ_XHAT)
#define SZ_HBUF   (2*2*BB*HID*2)             // 524,288
#define OFF_HFIN  (OFF_HBUF + SZ_HBUF)
#define SZ_HFIN   (2*BB*HID*4)               // 524,288
#define OFF_FLAGS (OFF_HFIN + SZ_HFIN)
#define SZ_FLAGS  (2*8*8*32*4)               // 16,384

__global__ void pack_kernel(const float* __restrict__ Wf, const float* __restrict__ Uf,
                            const float* __restrict__ bf,
                            const float* __restrict__ Wb, const float* __restrict__ Ub,
                            const float* __restrict__ bb,
                            __hip_bfloat16* __restrict__ WUp, float* __restrict__ bp) {
    int flat = blockIdx.x * 256 + threadIdx.x;          // [0, 2*8*4*32*384)
    int k = flat % 384;
    int rest = flat / 384;                              // [dir][jg][gate][jc]
    int jc   = rest & 31;
    int gate = (rest >> 5) & 3;
    int jg   = (rest >> 7) & 7;
    int dir  = rest >> 10;
    int J = gate * 256 + jg * 32 + jc;
    const float* W = dir ? Wb : Wf;
    const float* U = dir ? Ub : Uf;
    float v = (k < 128) ? W[(size_t)k * G4 + J] : U[(size_t)(k - 128) * G4 + J];
    WUp[flat] = __float2bfloat16(v);
    if (k == 0) {
        const float* bias = dir ? bb : bf;
        bp[rest] = bias[J];
    }
}

__global__ void gather_kernel(const int* __restrict__ inputs, const float* __restrict__ embed,
                              __hip_bfloat16* __restrict__ xhat) {
    int row = blockIdx.x * 2 + (threadIdx.x >> 7);      // [0, B*T)
    int col = threadIdx.x & 127;
    int tok = inputs[row];
    xhat[(size_t)row * EMBED + col] = __float2bfloat16(embed[(size_t)tok * EMBED + col]);
}

// Zero the flags through the SAME bypass path (sc0 sc1) the lstm kernel uses,
// so the zeros are visible to bypass loads regardless of L2 state.
__global__ void init_flags_kernel(int* __restrict__ flags) {
    int i = blockIdx.x * 256 + threadIdx.x;             // 4096 entries
    int* p = flags + i;
    unsigned z = 0;
    asm volatile("global_store_dword %0, %1, off sc0 sc1" :: "v"(p), "v"(z) : "memory");
}

__device__ __forceinline__ float sigf(float x) { return 1.f / (1.f + __expf(-x)); }

__launch_bounds__(256, 1)
__global__ void lstm_kernel(const int* __restrict__ inputs,
                            const __hip_bfloat16* __restrict__ xhat,
                            const __hip_bfloat16* __restrict__ WUp,
                            const float* __restrict__ bp,
                            __hip_bfloat16* __restrict__ hbuf,
                            float* __restrict__ hfinal,
                            int* __restrict__ flags) {
    const int bid = blockIdx.x;          // 128 blocks = 2 dir x 8 jg x 8 bg
    const int dir = bid >> 6;
    const int jg  = (bid >> 3) & 7;
    const int bg  = bid & 7;
    const int tid = threadIdx.x;
    const int wid = tid >> 6;            // wave 0..3
    const int lane = tid & 63;
    const int l15 = lane & 15, lhi = lane >> 4;
    const int jch = wid & 1;             // jc half: cols jch*16 + l15
    const int mrow0 = bg * 32 + (wid >> 1) * 16;   // m-tile base (batch)

    // ---- preload weights: 4 gates x 12 k-tiles ----
    short8 wfrag[4][12];
    const short* wu = (const short*)WUp + (size_t)(dir * 8 + jg) * 4 * 32 * 384;
#pragma unroll
    for (int g = 0; g < 4; ++g)
#pragma unroll
        for (int kt = 0; kt < 12; ++kt)
            wfrag[g][kt] = *(const short8*)(wu + (size_t)(g * 32 + jch * 16 + l15) * 384 + kt * 32 + 8 * lhi);

    float bias[4];
#pragma unroll
    for (int g = 0; g < 4; ++g)
        bias[g] = bp[((dir * 8 + jg) * 4 + g) * 32 + jch * 16 + l15];

    float c_st[4] = {0, 0, 0, 0};
    float h_st[4] = {0, 0, 0, 0};
    const int brow0 = mrow0 + 4 * lhi;   // rows brow0..brow0+3

    int* myflag = flags + ((dir * 8 + jg) * 8 + bg) * 32;
    int* pollp  = flags + ((dir * 8 + (lane & 7)) * 8 + bg) * 32;  // 8 producers of (dir,bg)

    const short* xrow = (const short*)xhat + (size_t)(mrow0 + l15) * TT * EMBED;
    const short* hb   = (const short*)hbuf + (size_t)dir * 2 * BB * HID;

    // preload x fragments for step 0 (normal cached loads)
    short8 xf[4];
    {
        const int t0 = dir ? (TT - 1) : 0;
#pragma unroll
        for (int kt = 0; kt < 4; ++kt)
            xf[kt] = *(const short8*)(xrow + (size_t)t0 * EMBED + kt * 32 + 8 * lhi);
    }

    for (int s = 0; s < TT; ++s) {
        const int t = dir ? (TT - 1 - s) : s;

        // ---- x-part of z: uses xf prefetched last iteration ----
        f32x4 acc[4] = {{0,0,0,0},{0,0,0,0},{0,0,0,0},{0,0,0,0}};
#pragma unroll
        for (int kt = 0; kt < 4; ++kt)
#pragma unroll
            for (int g = 0; g < 4; ++g)
                acc[g] = __builtin_amdgcn_mfma_f32_16x16x32_bf16(xf[kt], wfrag[g][kt], acc[g], 0, 0, 0);

        // ---- wait for h(s): relaxed bypass polls, no cache maintenance ----
        {
            unsigned fv;
            do {
                asm volatile("global_load_dword %0, %1, off sc0 sc1\n\t"
                             "s_waitcnt vmcnt(0)"
                             : "=v"(fv) : "v"(pollp) : "memory");
            } while (__any((int)fv < (unsigned)s ? 1 : 0));
        }

        // ---- masks for this step (normal cached loads, L2-hot) ----
        int mk[4];
#pragma unroll
        for (int r = 0; r < 4; ++r)
            mk[r] = inputs[(size_t)(brow0 + r) * TT + t];

        // ---- h fragments via coherence-point bypass loads; h(0)=0 so skip s=0 ----
        if (s != 0) {
            short8 hf[8];
            const short* hbase = hb + (size_t)(s & 1) * BB * HID
                               + (size_t)(mrow0 + l15) * HID + 8 * lhi;
            asm volatile(
                "global_load_dwordx4 %0, %8, off sc0 sc1\n\t"
                "global_load_dwordx4 %1, %8, off offset:64 sc0 sc1\n\t"
                "global_load_dwordx4 %2, %8, off offset:128 sc0 sc1\n\t"
                "global_load_dwordx4 %3, %8, off offset:192 sc0 sc1\n\t"
                "global_load_dwordx4 %4, %8, off offset:256 sc0 sc1\n\t"
                "global_load_dwordx4 %5, %8, off offset:320 sc0 sc1\n\t"
                "global_load_dwordx4 %6, %8, off offset:384 sc0 sc1\n\t"
                "global_load_dwordx4 %7, %8, off offset:448 sc0 sc1\n\t"
                "s_waitcnt vmcnt(0)"
                : "=&v"(hf[0]), "=&v"(hf[1]), "=&v"(hf[2]), "=&v"(hf[3]),
                  "=&v"(hf[4]), "=&v"(hf[5]), "=&v"(hf[6]), "=&v"(hf[7])
                : "v"(hbase)
                : "memory");
            __builtin_amdgcn_sched_barrier(0);
#pragma unroll
            for (int kt = 4; kt < 12; ++kt)
#pragma unroll
                for (int g = 0; g < 4; ++g)
                    acc[g] = __builtin_amdgcn_mfma_f32_16x16x32_bf16(hf[kt - 4], wfrag[g][kt], acc[g], 0, 0, 0);
        }

        // ---- gates (wave-local) ----
        unsigned hw32[4];
#pragma unroll
        for (int r = 0; r < 4; ++r) {
            float zi = acc[0][r] + bias[0];
            float zf = acc[1][r] + bias[1];
            float zg = acc[2][r] + bias[2];
            float zo = acc[3][r] + bias[3];
            float cn = sigf(zf) * c_st[r] + sigf(zi) * tanhf(zg);
            float hn = sigf(zo) * tanhf(cn);
            if (mk[r] > 0) { c_st[r] = cn; h_st[r] = hn; }
            __hip_bfloat16 hbf = __float2bfloat16(h_st[r]);
            hw32[r] = *(unsigned short*)&hbf;
        }

        // ---- publish h(s+1) via bypass stores; vmcnt(0) = acked at coherence pt ----
        {
            const short* sbase = (const short*)hbuf + (size_t)dir * 2 * BB * HID
                               + (size_t)((s + 1) & 1) * BB * HID
                               + (size_t)brow0 * HID + jg * 32 + jch * 16 + l15;
            asm volatile(
                "global_store_short %4, %0, off sc0 sc1\n\t"
                "global_store_short %4, %1, off offset:512 sc0 sc1\n\t"
                "global_store_short %4, %2, off offset:1024 sc0 sc1\n\t"
                "global_store_short %4, %3, off offset:1536 sc0 sc1\n\t"
                "s_waitcnt vmcnt(0)"
                :: "v"(hw32[0]), "v"(hw32[1]), "v"(hw32[2]), "v"(hw32[3]), "v"(sbase)
                : "memory");
        }

        // ---- prefetch x for step s+1 (normal cached loads; latency hidden) ----
        if (s + 1 < TT) {
            const int tn = dir ? (TT - 2 - s) : (s + 1);
#pragma unroll
            for (int kt = 0; kt < 4; ++kt)
                xf[kt] = *(const short8*)(xrow + (size_t)tn * EMBED + kt * 32 + 8 * lhi);
        }

        __syncthreads();   // all 4 waves' h stores are acked before the flag
        if (tid == 0) {
            unsigned val = (unsigned)(s + 1);
            asm volatile("global_store_dword %0, %1, off sc0 sc1"
                         :: "v"(myflag), "v"(val) : "memory");
        }
    }

#pragma unroll
    for (int r = 0; r < 4; ++r)
        hfinal[((size_t)dir * BB + brow0 + r) * HID + jg * 32 + jch * 16 + l15] = h_st[r];
}

__global__ void epilogue_kernel(const int* __restrict__ input_end,
                                const float* __restrict__ hfinal,
                                const float* __restrict__ cls_W, const float* __restrict__ cls_b,
                                const float* __restrict__ ent_W, const float* __restrict__ ent_b,
                                float* __restrict__ out) {
    int b = blockIdx.x;
    int lane = threadIdx.x;   // 64 threads
    int ie = input_end[b];
    float pe0 = 0, pe1 = 0, pe2 = 0, pc = 0;
    for (int k = lane; k < 2 * HID; k += 64) {
        float bv, se;
        if (k < HID) {
            bv = hfinal[(size_t)b * HID + k];
            se = hfinal[(size_t)ie * HID + k];
        } else {
            bv = hfinal[(size_t)(BB + b) * HID + (k - HID)];
            se = hfinal[(size_t)(BB + ie) * HID + (k - HID)];
        }
        pe0 += bv * ent_W[k * 3 + 0];
        pe1 += bv * ent_W[k * 3 + 1];
        pe2 += bv * ent_W[k * 3 + 2];
        pc  += se * cls_W[k];
    }
    for (int off = 32; off; off >>= 1) {
        pe0 += __shfl_down(pe0, off);
        pe1 += __shfl_down(pe1, off);
        pe2 += __shfl_down(pe2, off);
        pc  += __shfl_down(pc, off);
    }
    if (lane == 0) {
        float l0 = pe0 + ent_b[0], l1 = pe1 + ent_b[1], l2 = pe2 + ent_b[2];
        float m = fmaxf(l0, fmaxf(l1, l2));
        float e0 = __expf(l0 - m), e1 = __expf(l1 - m), e2 = __expf(l2 - m);
        float ssum = e0 + e1 + e2;
        out[256 + b * 3 + 0] = e0 / ssum;
        out[256 + b * 3 + 1] = e1 / ssum;
        out[256 + b * 3 + 2] = e2 / ssum;
        float cl = pc + cls_b[0];
        out[b] = 1.f / (1.f + __expf(-cl));
    }
}

extern "C" void kernel_launch(void* const* d_in, const int* in_sizes, int n_in,
                              void* d_out, int out_size, void* d_ws, size_t ws_size,
                              hipStream_t stream) {
    const int*   inputs    = (const int*)d_in[0];
    const int*   input_end = (const int*)d_in[1];
    const float* embed     = (const float*)d_in[2];
    const float* Wf        = (const float*)d_in[3];
    const float* Uf        = (const float*)d_in[4];
    const float* bf        = (const float*)d_in[5];
    const float* Wb        = (const float*)d_in[6];
    const float* Ub        = (const float*)d_in[7];
    const float* bb        = (const float*)d_in[8];
    const float* cls_W     = (const float*)d_in[9];
    const float* cls_b     = (const float*)d_in[10];
    const float* ent_W     = (const float*)d_in[11];
    const float* ent_b     = (const float*)d_in[12];
    float* out = (float*)d_out;

    char* ws = (char*)d_ws;
    __hip_bfloat16* WUp    = (__hip_bfloat16*)(ws + OFF_WUP);
    float*          bp     = (float*)(ws + OFF_BP);
    __hip_bfloat16* xhat   = (__hip_bfloat16*)(ws + OFF_XHAT);
    __hip_bfloat16* hbuf   = (__hip_bfloat16*)(ws + OFF_HBUF);
    float*          hfinal = (float*)(ws + OFF_HFIN);
    int*            flags  = (int*)(ws + OFF_FLAGS);

    init_flags_kernel<<<16, 256, 0, stream>>>(flags);
    pack_kernel<<<3072, 256, 0, stream>>>(Wf, Uf, bf, Wb, Ub, bb, WUp, bp);
    gather_kernel<<<BB * TT / 2, 256, 0, stream>>>(inputs, embed, xhat);

    void* args[] = {(void*)&inputs, (void*)&xhat, (void*)&WUp, (void*)&bp,
                    (void*)&hbuf, (void*)&hfinal, (void*)&flags};
    hipLaunchCooperativeKernel((void*)lstm_kernel, dim3(128), dim3(256), args, 0, stream);

    epilogue_kernel<<<BB, 64, 0, stream>>>(input_end, hfinal, cls_W, cls_b, ent_W, ent_b, out);
}